// Round 1
// baseline (1295.534 us; speedup 1.0000x reference)
//
#include <hip/hip_runtime.h>

// Problem constants (fixed by the reference):
// B=8, C=256, H=W=48 -> N=2304, k=4 -> CK=64
#define BATCH 8
#define CIN   256
#define NPIX  2304
#define CKD   64

// ---------------------------------------------------------------------------
// Generic conv1x1 as GEMM: out[b,o,n] = sum_c W[o,c]*x[b,c,n] + bias[o]
// grid (N/64, O/64, B), block (16,16); 64x64 tile, 4x4 per thread.
// ---------------------------------------------------------------------------
__global__ __launch_bounds__(256) void conv1x1_gemm(
    const float* __restrict__ x, const float* __restrict__ W,
    const float* __restrict__ bias, float* __restrict__ out,
    int Cin, int N)
{
    __shared__ float as[64][65];   // W tile [o][c], padded (scalar broadcast reads)
    __shared__ float xs[64][64];   // x tile [c][n]
    const int tx = threadIdx.x, ty = threadIdx.y;
    const int t  = ty * 16 + tx;
    const int n0 = blockIdx.x * 64, o0 = blockIdx.y * 64, b = blockIdx.z;
    const int O  = gridDim.y * 64;
    const float* xb = x + (size_t)b * Cin * N;

    float acc[4][4] = {};
    for (int c0 = 0; c0 < Cin; c0 += 64) {
        __syncthreads();
        #pragma unroll
        for (int it = 0; it < 16; ++it) {
            int flat = it * 256 + t;
            int row = flat >> 6, col = flat & 63;
            as[row][col] = W[(size_t)(o0 + row) * Cin + c0 + col];
            xs[row][col] = xb[(size_t)(c0 + row) * N + n0 + col];
        }
        __syncthreads();
        #pragma unroll
        for (int cc = 0; cc < 64; ++cc) {
            float4 xv = *(const float4*)&xs[cc][tx * 4];
            float a0 = as[ty * 4 + 0][cc];
            float a1 = as[ty * 4 + 1][cc];
            float a2 = as[ty * 4 + 2][cc];
            float a3 = as[ty * 4 + 3][cc];
            acc[0][0] += a0 * xv.x; acc[0][1] += a0 * xv.y; acc[0][2] += a0 * xv.z; acc[0][3] += a0 * xv.w;
            acc[1][0] += a1 * xv.x; acc[1][1] += a1 * xv.y; acc[1][2] += a1 * xv.z; acc[1][3] += a1 * xv.w;
            acc[2][0] += a2 * xv.x; acc[2][1] += a2 * xv.y; acc[2][2] += a2 * xv.z; acc[2][3] += a2 * xv.w;
            acc[3][0] += a3 * xv.x; acc[3][1] += a3 * xv.y; acc[3][2] += a3 * xv.z; acc[3][3] += a3 * xv.w;
        }
    }
    #pragma unroll
    for (int a = 0; a < 4; ++a) {
        int o = o0 + ty * 4 + a;
        float bv = bias[o];
        float4 r;
        r.x = acc[a][0] + bv; r.y = acc[a][1] + bv;
        r.z = acc[a][2] + bv; r.w = acc[a][3] + bv;
        *(float4*)&out[((size_t)b * O + o) * N + n0 + tx * 4] = r;
    }
}

// ---------------------------------------------------------------------------
// Energy row sums: S[b,i] += sum over j-tile of exp(q_i . k_j)
// grid (N/64 (j), N/64 (i), B), block (16,16). S must be pre-zeroed.
// ---------------------------------------------------------------------------
__global__ __launch_bounds__(256) void energy_rowsum(
    const float* __restrict__ q, const float* __restrict__ k,
    float* __restrict__ S, int N)
{
    __shared__ float qs[64][64];   // [ck][i]
    __shared__ float ks[64][64];   // [ck][j]
    __shared__ float red[64][17];
    const int tx = threadIdx.x, ty = threadIdx.y;
    const int t  = ty * 16 + tx;
    const int j0 = blockIdx.x * 64, i0 = blockIdx.y * 64, b = blockIdx.z;
    const float* qb = q + (size_t)b * CKD * N;
    const float* kb = k + (size_t)b * CKD * N;

    #pragma unroll
    for (int it = 0; it < 16; ++it) {
        int flat = it * 256 + t;
        int row = flat >> 6, col = flat & 63;
        qs[row][col] = qb[(size_t)row * N + i0 + col];
        ks[row][col] = kb[(size_t)row * N + j0 + col];
    }
    __syncthreads();

    float acc[4][4] = {};
    #pragma unroll
    for (int ck = 0; ck < 64; ++ck) {
        float4 qv = *(const float4*)&qs[ck][ty * 4];
        float4 kv = *(const float4*)&ks[ck][tx * 4];
        acc[0][0] += qv.x * kv.x; acc[0][1] += qv.x * kv.y; acc[0][2] += qv.x * kv.z; acc[0][3] += qv.x * kv.w;
        acc[1][0] += qv.y * kv.x; acc[1][1] += qv.y * kv.y; acc[1][2] += qv.y * kv.z; acc[1][3] += qv.y * kv.w;
        acc[2][0] += qv.z * kv.x; acc[2][1] += qv.z * kv.y; acc[2][2] += qv.z * kv.z; acc[2][3] += qv.z * kv.w;
        acc[3][0] += qv.w * kv.x; acc[3][1] += qv.w * kv.y; acc[3][2] += qv.w * kv.z; acc[3][3] += qv.w * kv.w;
    }
    #pragma unroll
    for (int a = 0; a < 4; ++a) {
        float rs = __expf(acc[a][0]) + __expf(acc[a][1]) + __expf(acc[a][2]) + __expf(acc[a][3]);
        red[ty * 4 + a][tx] = rs;
    }
    __syncthreads();
    if (t < 64) {
        float s = 0.f;
        #pragma unroll
        for (int x2 = 0; x2 < 16; ++x2) s += red[t][x2];
        atomicAdd(&S[(size_t)b * N + i0 + t], s);
    }
}

__global__ __launch_bounds__(256) void recip_kernel(
    const float* __restrict__ S, float* __restrict__ invS, int n)
{
    int i = blockIdx.x * 256 + threadIdx.x;
    if (i < n) invS[i] = 1.0f / S[i];
}

// ---------------------------------------------------------------------------
// Fused attention bmm: out1[b,c,j] = sum_i (v[c,i]*invS[i]) * exp(q_i . k_j)
// grid (N/64 (j), C/64 (c), B), block (16,16).
// Recomputes the exp-energy 64x64 tile in LDS per i-chunk (no E materialization).
// ---------------------------------------------------------------------------
__global__ __launch_bounds__(256) void attn_bmm(
    const float* __restrict__ q, const float* __restrict__ k,
    const float* __restrict__ v, const float* __restrict__ invS,
    float* __restrict__ out1, int N)
{
    __shared__ float ks[64][64];     // [ck][j], loaded once
    __shared__ float es[64][64];     // exp-energy tile [i][j]
    __shared__ float un[64 * 65];    // union: q tile (stride 64) / u tile (stride 65)
    const int tx = threadIdx.x, ty = threadIdx.y;
    const int t  = ty * 16 + tx;
    const int j0 = blockIdx.x * 64, c0 = blockIdx.y * 64, b = blockIdx.z;
    const float* qb  = q + (size_t)b * CKD * N;
    const float* kb  = k + (size_t)b * CKD * N;
    const float* vb  = v + (size_t)b * CIN * N;
    const float* isb = invS + (size_t)b * N;

    #pragma unroll
    for (int it = 0; it < 16; ++it) {
        int flat = it * 256 + t;
        int row = flat >> 6, col = flat & 63;
        ks[row][col] = kb[(size_t)row * N + j0 + col];
    }

    float acc[4][4] = {};
    for (int i0 = 0; i0 < N; i0 += 64) {
        __syncthreads();   // prev GEMM done (and first-iter ks staging ordered below)
        // stage q tile: un[ck*64 + i]
        #pragma unroll
        for (int it = 0; it < 16; ++it) {
            int flat = it * 256 + t;
            int row = flat >> 6, col = flat & 63;
            un[row * 64 + col] = qb[(size_t)row * N + i0 + col];
        }
        __syncthreads();
        // energy tile: e[a][bb] for (i = i0+4ty+a, j = j0+4tx+bb)
        float e[4][4] = {};
        #pragma unroll
        for (int ck = 0; ck < 64; ++ck) {
            float4 qv = *(const float4*)&un[ck * 64 + ty * 4];
            float4 kv = *(const float4*)&ks[ck][tx * 4];
            e[0][0] += qv.x * kv.x; e[0][1] += qv.x * kv.y; e[0][2] += qv.x * kv.z; e[0][3] += qv.x * kv.w;
            e[1][0] += qv.y * kv.x; e[1][1] += qv.y * kv.y; e[1][2] += qv.y * kv.z; e[1][3] += qv.y * kv.w;
            e[2][0] += qv.z * kv.x; e[2][1] += qv.z * kv.y; e[2][2] += qv.z * kv.z; e[2][3] += qv.z * kv.w;
            e[3][0] += qv.w * kv.x; e[3][1] += qv.w * kv.y; e[3][2] += qv.w * kv.z; e[3][3] += qv.w * kv.w;
        }
        #pragma unroll
        for (int a = 0; a < 4; ++a) {
            float4 ev;
            ev.x = __expf(e[a][0]); ev.y = __expf(e[a][1]);
            ev.z = __expf(e[a][2]); ev.w = __expf(e[a][3]);
            *(float4*)&es[ty * 4 + a][tx * 4] = ev;
        }
        __syncthreads();   // energy reads of un done; es fully written
        // stage u tile = v/S into un with stride 65: un[c*65 + i]
        #pragma unroll
        for (int it = 0; it < 16; ++it) {
            int flat = it * 256 + t;
            int row = flat >> 6, col = flat & 63;
            un[row * 65 + col] = vb[(size_t)(c0 + row) * N + i0 + col] * isb[i0 + col];
        }
        __syncthreads();
        // out_tile[c,j] += u[c,i] * es[i,j]
        #pragma unroll
        for (int ii = 0; ii < 64; ++ii) {
            float4 ev = *(const float4*)&es[ii][tx * 4];
            float u0 = un[(ty * 4 + 0) * 65 + ii];
            float u1 = un[(ty * 4 + 1) * 65 + ii];
            float u2 = un[(ty * 4 + 2) * 65 + ii];
            float u3 = un[(ty * 4 + 3) * 65 + ii];
            acc[0][0] += u0 * ev.x; acc[0][1] += u0 * ev.y; acc[0][2] += u0 * ev.z; acc[0][3] += u0 * ev.w;
            acc[1][0] += u1 * ev.x; acc[1][1] += u1 * ev.y; acc[1][2] += u1 * ev.z; acc[1][3] += u1 * ev.w;
            acc[2][0] += u2 * ev.x; acc[2][1] += u2 * ev.y; acc[2][2] += u2 * ev.z; acc[2][3] += u2 * ev.w;
            acc[3][0] += u3 * ev.x; acc[3][1] += u3 * ev.y; acc[3][2] += u3 * ev.z; acc[3][3] += u3 * ev.w;
        }
    }
    #pragma unroll
    for (int a = 0; a < 4; ++a) {
        int c = c0 + ty * 4 + a;
        float4 r;
        r.x = acc[a][0]; r.y = acc[a][1]; r.z = acc[a][2]; r.w = acc[a][3];
        *(float4*)&out1[((size_t)b * CIN + c) * N + j0 + tx * 4] = r;
    }
}

// ---------------------------------------------------------------------------
extern "C" void kernel_launch(void* const* d_in, const int* in_sizes, int n_in,
                              void* d_out, int out_size, void* d_ws, size_t ws_size,
                              hipStream_t stream) {
    const float* x  = (const float*)d_in[0];
    const float* qw = (const float*)d_in[1];
    const float* qb = (const float*)d_in[2];
    const float* kw = (const float*)d_in[3];
    const float* kb = (const float*)d_in[4];
    const float* vw = (const float*)d_in[5];
    const float* vb = (const float*)d_in[6];
    const float* gw = (const float*)d_in[7];
    const float* gb = (const float*)d_in[8];
    float* out = (float*)d_out;

    const size_t BCKN = (size_t)BATCH * CKD * NPIX;   // 1,179,648
    const size_t BCN  = (size_t)BATCH * CIN * NPIX;   // 4,718,592
    const size_t BN   = (size_t)BATCH * NPIX;         // 18,432

    float* q   = (float*)d_ws;
    float* kk  = q + BCKN;
    float* v   = kk + BCKN;
    float* S   = v + BCN;
    float* iS  = S + BN;
    float* o1  = iS + BN;
    // total ws: 11,833,344 floats ~= 47.3 MB

    hipMemsetAsync(S, 0, BN * sizeof(float), stream);

    dim3 blk(16, 16);
    conv1x1_gemm<<<dim3(NPIX / 64, CKD / 64, BATCH), blk, 0, stream>>>(x, qw, qb, q, CIN, NPIX);
    conv1x1_gemm<<<dim3(NPIX / 64, CKD / 64, BATCH), blk, 0, stream>>>(x, kw, kb, kk, CIN, NPIX);
    conv1x1_gemm<<<dim3(NPIX / 64, CIN / 64, BATCH), blk, 0, stream>>>(x, vw, vb, v, CIN, NPIX);
    energy_rowsum<<<dim3(NPIX / 64, NPIX / 64, BATCH), blk, 0, stream>>>(q, kk, S, NPIX);
    recip_kernel<<<(int)((BN + 255) / 256), 256, 0, stream>>>(S, iS, (int)BN);
    attn_bmm<<<dim3(NPIX / 64, CIN / 64, BATCH), blk, 0, stream>>>(q, kk, v, iS, o1, NPIX);
    conv1x1_gemm<<<dim3(NPIX / 64, CIN / 64, BATCH), blk, 0, stream>>>(o1, gw, gb, out, CIN, NPIX);
}

// Round 2
// 489.277 us; speedup vs baseline: 2.6479x; 2.6479x over previous
//
#include <hip/hip_runtime.h>

// Problem constants (fixed by the reference):
// B=8, C=256, H=W=48 -> N=2304, k=4 -> CK=64
#define BATCH 8
#define CIN   256
#define NPIX  2304
#define CKD   64

typedef _Float16 f16;
typedef __attribute__((ext_vector_type(4))) _Float16 f16x4;
typedef __attribute__((ext_vector_type(8))) _Float16 f16x8;
typedef __attribute__((ext_vector_type(4))) float    f32x4;

// ---------------------------------------------------------------------------
// Generic conv1x1 as GEMM: out[b,o,n] = sum_c W[o,c]*x[b,c,n] + bias[o]
// grid (N/64, O/64, B), block (16,16); 64x64 tile, 4x4 per thread.
// ---------------------------------------------------------------------------
__global__ __launch_bounds__(256) void conv1x1_gemm(
    const float* __restrict__ x, const float* __restrict__ W,
    const float* __restrict__ bias, float* __restrict__ out,
    int Cin, int N)
{
    __shared__ float as[64][65];   // W tile [o][c], padded (scalar broadcast reads)
    __shared__ float xs[64][64];   // x tile [c][n]
    const int tx = threadIdx.x, ty = threadIdx.y;
    const int t  = ty * 16 + tx;
    const int n0 = blockIdx.x * 64, o0 = blockIdx.y * 64, b = blockIdx.z;
    const int O  = gridDim.y * 64;
    const float* xb = x + (size_t)b * Cin * N;

    float acc[4][4] = {};
    for (int c0 = 0; c0 < Cin; c0 += 64) {
        __syncthreads();
        #pragma unroll
        for (int it = 0; it < 16; ++it) {
            int flat = it * 256 + t;
            int row = flat >> 6, col = flat & 63;
            as[row][col] = W[(size_t)(o0 + row) * Cin + c0 + col];
            xs[row][col] = xb[(size_t)(c0 + row) * N + n0 + col];
        }
        __syncthreads();
        #pragma unroll
        for (int cc = 0; cc < 64; ++cc) {
            float4 xv = *(const float4*)&xs[cc][tx * 4];
            float a0 = as[ty * 4 + 0][cc];
            float a1 = as[ty * 4 + 1][cc];
            float a2 = as[ty * 4 + 2][cc];
            float a3 = as[ty * 4 + 3][cc];
            acc[0][0] += a0 * xv.x; acc[0][1] += a0 * xv.y; acc[0][2] += a0 * xv.z; acc[0][3] += a0 * xv.w;
            acc[1][0] += a1 * xv.x; acc[1][1] += a1 * xv.y; acc[1][2] += a1 * xv.z; acc[1][3] += a1 * xv.w;
            acc[2][0] += a2 * xv.x; acc[2][1] += a2 * xv.y; acc[2][2] += a2 * xv.z; acc[2][3] += a2 * xv.w;
            acc[3][0] += a3 * xv.x; acc[3][1] += a3 * xv.y; acc[3][2] += a3 * xv.z; acc[3][3] += a3 * xv.w;
        }
    }
    #pragma unroll
    for (int a = 0; a < 4; ++a) {
        int o = o0 + ty * 4 + a;
        float bv = bias[o];
        float4 r;
        r.x = acc[a][0] + bv; r.y = acc[a][1] + bv;
        r.z = acc[a][2] + bv; r.w = acc[a][3] + bv;
        *(float4*)&out[((size_t)b * O + o) * N + n0 + tx * 4] = r;
    }
}

// ---------------------------------------------------------------------------
// Energy: e[i,j] = exp(q_i . k_j) in fp32.
//  - accumulates row sums S[b,i] (atomicAdd per tile, fp32 exact)
//  - stores Et[b, j, i] = e[i,j] as fp16 (TRANSPOSED: contiguous in i) for the
//    MFMA bmm's B-fragment loads.
// grid (N/64 (j), N/64 (i), B), block (16,16). S must be pre-zeroed.
// ---------------------------------------------------------------------------
__global__ __launch_bounds__(256) void energy_rowsum(
    const float* __restrict__ q, const float* __restrict__ k,
    float* __restrict__ S, f16* __restrict__ Et, int N)
{
    __shared__ float qs[64][64];   // [ck][i]
    __shared__ float ks[64][64];   // [ck][j]
    __shared__ float red[64][17];
    const int tx = threadIdx.x, ty = threadIdx.y;
    const int t  = ty * 16 + tx;
    const int j0 = blockIdx.x * 64, i0 = blockIdx.y * 64, b = blockIdx.z;
    const float* qb = q + (size_t)b * CKD * N;
    const float* kb = k + (size_t)b * CKD * N;

    #pragma unroll
    for (int it = 0; it < 16; ++it) {
        int flat = it * 256 + t;
        int row = flat >> 6, col = flat & 63;
        qs[row][col] = qb[(size_t)row * N + i0 + col];
        ks[row][col] = kb[(size_t)row * N + j0 + col];
    }
    __syncthreads();

    float acc[4][4] = {};
    #pragma unroll
    for (int ck = 0; ck < 64; ++ck) {
        float4 qv = *(const float4*)&qs[ck][ty * 4];
        float4 kv = *(const float4*)&ks[ck][tx * 4];
        acc[0][0] += qv.x * kv.x; acc[0][1] += qv.x * kv.y; acc[0][2] += qv.x * kv.z; acc[0][3] += qv.x * kv.w;
        acc[1][0] += qv.y * kv.x; acc[1][1] += qv.y * kv.y; acc[1][2] += qv.y * kv.z; acc[1][3] += qv.y * kv.w;
        acc[2][0] += qv.z * kv.x; acc[2][1] += qv.z * kv.y; acc[2][2] += qv.z * kv.z; acc[2][3] += qv.z * kv.w;
        acc[3][0] += qv.w * kv.x; acc[3][1] += qv.w * kv.y; acc[3][2] += qv.w * kv.z; acc[3][3] += qv.w * kv.w;
    }

    float ex[4][4];
    #pragma unroll
    for (int a = 0; a < 4; ++a)
        #pragma unroll
        for (int bb = 0; bb < 4; ++bb)
            ex[a][bb] = __expf(acc[a][bb]);

    // transposed fp16 store: Et[j][i0+4ty .. +3], 8B per store
    const size_t ebase = (size_t)b * N * N;
    #pragma unroll
    for (int bb = 0; bb < 4; ++bb) {
        int j = j0 + 4 * tx + bb;
        f16x4 h = { (f16)ex[0][bb], (f16)ex[1][bb], (f16)ex[2][bb], (f16)ex[3][bb] };
        *(f16x4*)&Et[ebase + (size_t)j * N + i0 + 4 * ty] = h;
    }

    #pragma unroll
    for (int a = 0; a < 4; ++a)
        red[ty * 4 + a][tx] = ex[a][0] + ex[a][1] + ex[a][2] + ex[a][3];
    __syncthreads();
    if (t < 64) {
        float s = 0.f;
        #pragma unroll
        for (int x2 = 0; x2 < 16; ++x2) s += red[t][x2];
        atomicAdd(&S[(size_t)b * N + i0 + t], s);
    }
}

__global__ __launch_bounds__(256) void recip_kernel(
    const float* __restrict__ S, float* __restrict__ invS, int n)
{
    int i = blockIdx.x * 256 + threadIdx.x;
    if (i < n) invS[i] = 1.0f / S[i];
}

// ---------------------------------------------------------------------------
// u[b,c,i] = v[b,c,i] * invS[b,i], stored fp16. 4 elems/thread, vectorized.
// ---------------------------------------------------------------------------
__global__ __launch_bounds__(256) void make_u(
    const float* __restrict__ v, const float* __restrict__ invS,
    f16* __restrict__ u)
{
    size_t idx = ((size_t)blockIdx.x * 256 + threadIdx.x) * 4;
    int i  = (int)(idx % NPIX);
    int b  = (int)(idx / ((size_t)CIN * NPIX));
    float4 vv = *(const float4*)(v + idx);
    float4 s  = *(const float4*)(invS + (size_t)b * NPIX + i);
    f16x4 h = { (f16)(vv.x * s.x), (f16)(vv.y * s.y),
                (f16)(vv.z * s.z), (f16)(vv.w * s.w) };
    *(f16x4*)(u + idx) = h;
}

// ---------------------------------------------------------------------------
// MFMA bmm: out1[b,c,j] = sum_i u[b,c,i] * Et[b,j,i]
// v_mfma_f32_16x16x32_f16:
//   A-frag (lane): A[m=lane&15][k=quad*8+j], j=0..7  -> u row, 16B contiguous
//   B-frag (lane): B[k=quad*8+j][n=lane&15]          -> Et row, 16B contiguous
//   C/D: col(n)=lane&15, row(m)=quad*4+reg
// Block = 256 thr = 4 waves; wave w covers m in [64w,64w+64) (4 m-tiles),
// block covers n-strip of 32 (2 n-tiles). grid (N/32, B) = (72, 8).
// ---------------------------------------------------------------------------
__global__ __launch_bounds__(256) void bmm_mfma(
    const f16* __restrict__ u, const f16* __restrict__ Et,
    float* __restrict__ out1)
{
    const int t    = threadIdx.x;
    const int wave = t >> 6, lane = t & 63;
    const int quad = lane >> 4, l16 = lane & 15;
    const int n0 = blockIdx.x * 32;
    const int b  = blockIdx.y;
    const f16* ub = u  + (size_t)b * CIN * NPIX;
    const f16* eb = Et + (size_t)b * NPIX * NPIX;
    const int mb = wave * 64;

    f32x4 acc[4][2];
    #pragma unroll
    for (int mt = 0; mt < 4; ++mt)
        #pragma unroll
        for (int nt = 0; nt < 2; ++nt)
            acc[mt][nt] = (f32x4){0.f, 0.f, 0.f, 0.f};

    const f16* ap = ub + (size_t)(mb + l16) * NPIX + quad * 8;
    const f16* bp = eb + (size_t)(n0 + l16) * NPIX + quad * 8;

    #pragma unroll 2
    for (int k0 = 0; k0 < NPIX; k0 += 32) {
        f16x8 af[4], bf[2];
        #pragma unroll
        for (int mt = 0; mt < 4; ++mt)
            af[mt] = *(const f16x8*)(ap + (size_t)mt * 16 * NPIX + k0);
        #pragma unroll
        for (int nt = 0; nt < 2; ++nt)
            bf[nt] = *(const f16x8*)(bp + (size_t)nt * 16 * NPIX + k0);
        #pragma unroll
        for (int mt = 0; mt < 4; ++mt)
            #pragma unroll
            for (int nt = 0; nt < 2; ++nt)
                acc[mt][nt] = __builtin_amdgcn_mfma_f32_16x16x32_f16(
                    af[mt], bf[nt], acc[mt][nt], 0, 0, 0);
    }

    #pragma unroll
    for (int mt = 0; mt < 4; ++mt)
        #pragma unroll
        for (int r = 0; r < 4; ++r) {
            int c = mb + mt * 16 + quad * 4 + r;
            #pragma unroll
            for (int nt = 0; nt < 2; ++nt) {
                int j = n0 + nt * 16 + l16;
                out1[((size_t)b * CIN + c) * NPIX + j] = acc[mt][nt][r];
            }
        }
}

// ---------------------------------------------------------------------------
extern "C" void kernel_launch(void* const* d_in, const int* in_sizes, int n_in,
                              void* d_out, int out_size, void* d_ws, size_t ws_size,
                              hipStream_t stream) {
    const float* x  = (const float*)d_in[0];
    const float* qw = (const float*)d_in[1];
    const float* qb = (const float*)d_in[2];
    const float* kw = (const float*)d_in[3];
    const float* kb = (const float*)d_in[4];
    const float* vw = (const float*)d_in[5];
    const float* vb = (const float*)d_in[6];
    const float* gw = (const float*)d_in[7];
    const float* gb = (const float*)d_in[8];
    float* out = (float*)d_out;

    const size_t BCKN = (size_t)BATCH * CKD * NPIX;   // 1,179,648
    const size_t BCN  = (size_t)BATCH * CIN * NPIX;   // 4,718,592
    const size_t BN   = (size_t)BATCH * NPIX;         // 18,432
    const size_t BNN  = (size_t)BATCH * NPIX * NPIX;  // 42,467,328

    // ws layout (total ~141.7 MB):
    f16*   Et = (f16*)d_ws;        // 84.93 MB
    f16*   u  = Et + BNN;          // 9.44 MB
    float* q  = (float*)(u + BCN); // fp32 section, 47.33 MB
    float* kk = q + BCKN;
    float* v  = kk + BCKN;
    float* S  = v + BCN;
    float* iS = S + BN;
    float* o1 = iS + BN;

    hipMemsetAsync(S, 0, BN * sizeof(float), stream);

    dim3 blk(16, 16);
    conv1x1_gemm<<<dim3(NPIX / 64, CKD / 64, BATCH), blk, 0, stream>>>(x, qw, qb, q, CIN, NPIX);
    conv1x1_gemm<<<dim3(NPIX / 64, CKD / 64, BATCH), blk, 0, stream>>>(x, kw, kb, kk, CIN, NPIX);
    conv1x1_gemm<<<dim3(NPIX / 64, CIN / 64, BATCH), blk, 0, stream>>>(x, vw, vb, v, CIN, NPIX);
    energy_rowsum<<<dim3(NPIX / 64, NPIX / 64, BATCH), blk, 0, stream>>>(q, kk, S, Et, NPIX);
    recip_kernel<<<(int)((BN + 255) / 256), 256, 0, stream>>>(S, iS, (int)BN);
    make_u<<<(int)(BCN / 4 / 256), 256, 0, stream>>>(v, iS, u);
    bmm_mfma<<<dim3(NPIX / 32, BATCH), 256, 0, stream>>>(u, Et, o1);
    conv1x1_gemm<<<dim3(NPIX / 64, CIN / 64, BATCH), blk, 0, stream>>>(o1, gw, gb, out, CIN, NPIX);
}

// Round 3
// 371.508 us; speedup vs baseline: 3.4872x; 1.3170x over previous
//
#include <hip/hip_runtime.h>

// B=8, C=256, H=W=48 -> N=2304, k=4 -> CK=64
#define BATCH 8
#define CIN   256
#define NPIX  2304
#define CKD   64
#define KHALF (NPIX / 2)   // 1152

typedef _Float16 f16;
typedef __attribute__((ext_vector_type(4))) _Float16 f16x4;
typedef __attribute__((ext_vector_type(8))) _Float16 f16x8;
typedef __attribute__((ext_vector_type(4))) float    f32x4;

// ---------------------------------------------------------------------------
// conv1x1 as GEMM (fp32 out): out[b,o,n] = sum_c W[o,c]*x[b,c,n] + bias[o]
// grid (N/64, O/64, B), block (16,16)
// ---------------------------------------------------------------------------
__global__ __launch_bounds__(256) void conv1x1_gemm(
    const float* __restrict__ x, const float* __restrict__ W,
    const float* __restrict__ bias, float* __restrict__ out,
    int Cin, int N)
{
    __shared__ float as[64][65];
    __shared__ float xs[64][64];
    const int tx = threadIdx.x, ty = threadIdx.y;
    const int t  = ty * 16 + tx;
    const int n0 = blockIdx.x * 64, o0 = blockIdx.y * 64, b = blockIdx.z;
    const int O  = gridDim.y * 64;
    const float* xb = x + (size_t)b * Cin * N;

    float acc[4][4] = {};
    for (int c0 = 0; c0 < Cin; c0 += 64) {
        __syncthreads();
        #pragma unroll
        for (int it = 0; it < 16; ++it) {
            int flat = it * 256 + t;
            int row = flat >> 6, col = flat & 63;
            as[row][col] = W[(size_t)(o0 + row) * Cin + c0 + col];
            xs[row][col] = xb[(size_t)(c0 + row) * N + n0 + col];
        }
        __syncthreads();
        #pragma unroll
        for (int cc = 0; cc < 64; ++cc) {
            float4 xv = *(const float4*)&xs[cc][tx * 4];
            float a0 = as[ty * 4 + 0][cc];
            float a1 = as[ty * 4 + 1][cc];
            float a2 = as[ty * 4 + 2][cc];
            float a3 = as[ty * 4 + 3][cc];
            acc[0][0] += a0 * xv.x; acc[0][1] += a0 * xv.y; acc[0][2] += a0 * xv.z; acc[0][3] += a0 * xv.w;
            acc[1][0] += a1 * xv.x; acc[1][1] += a1 * xv.y; acc[1][2] += a1 * xv.z; acc[1][3] += a1 * xv.w;
            acc[2][0] += a2 * xv.x; acc[2][1] += a2 * xv.y; acc[2][2] += a2 * xv.z; acc[2][3] += a2 * xv.w;
            acc[3][0] += a3 * xv.x; acc[3][1] += a3 * xv.y; acc[3][2] += a3 * xv.z; acc[3][3] += a3 * xv.w;
        }
    }
    #pragma unroll
    for (int a = 0; a < 4; ++a) {
        int o = o0 + ty * 4 + a;
        float bv = bias[o];
        float4 r;
        r.x = acc[a][0] + bv; r.y = acc[a][1] + bv;
        r.z = acc[a][2] + bv; r.w = acc[a][3] + bv;
        *(float4*)&out[((size_t)b * O + o) * N + n0 + tx * 4] = r;
    }
}

// ---------------------------------------------------------------------------
// conv1x1 for q/k (O=64), output TRANSPOSED fp16: outT[b, n, o] (N x 64)
// grid (N/64, 1, B), block (16,16)
// ---------------------------------------------------------------------------
__global__ __launch_bounds__(256) void conv1x1_qk_f16t(
    const float* __restrict__ x, const float* __restrict__ W,
    const float* __restrict__ bias, f16* __restrict__ outT,
    int Cin, int N)
{
    __shared__ float as[64][65];
    __shared__ float xs[64][64];
    const int tx = threadIdx.x, ty = threadIdx.y;
    const int t  = ty * 16 + tx;
    const int n0 = blockIdx.x * 64, b = blockIdx.z;
    const float* xb = x + (size_t)b * Cin * N;

    float acc[4][4] = {};
    for (int c0 = 0; c0 < Cin; c0 += 64) {
        __syncthreads();
        #pragma unroll
        for (int it = 0; it < 16; ++it) {
            int flat = it * 256 + t;
            int row = flat >> 6, col = flat & 63;
            as[row][col] = W[(size_t)row * Cin + c0 + col];
            xs[row][col] = xb[(size_t)(c0 + row) * N + n0 + col];
        }
        __syncthreads();
        #pragma unroll
        for (int cc = 0; cc < 64; ++cc) {
            float4 xv = *(const float4*)&xs[cc][tx * 4];
            float a0 = as[ty * 4 + 0][cc];
            float a1 = as[ty * 4 + 1][cc];
            float a2 = as[ty * 4 + 2][cc];
            float a3 = as[ty * 4 + 3][cc];
            acc[0][0] += a0 * xv.x; acc[0][1] += a0 * xv.y; acc[0][2] += a0 * xv.z; acc[0][3] += a0 * xv.w;
            acc[1][0] += a1 * xv.x; acc[1][1] += a1 * xv.y; acc[1][2] += a1 * xv.z; acc[1][3] += a1 * xv.w;
            acc[2][0] += a2 * xv.x; acc[2][1] += a2 * xv.y; acc[2][2] += a2 * xv.z; acc[2][3] += a2 * xv.w;
            acc[3][0] += a3 * xv.x; acc[3][1] += a3 * xv.y; acc[3][2] += a3 * xv.z; acc[3][3] += a3 * xv.w;
        }
    }
    float b0 = bias[ty * 4 + 0], b1 = bias[ty * 4 + 1];
    float b2 = bias[ty * 4 + 2], b3 = bias[ty * 4 + 3];
    #pragma unroll
    for (int bb = 0; bb < 4; ++bb) {
        int n = n0 + 4 * tx + bb;
        f16x4 h = { (f16)(acc[0][bb] + b0), (f16)(acc[1][bb] + b1),
                    (f16)(acc[2][bb] + b2), (f16)(acc[3][bb] + b3) };
        *(f16x4*)&outT[((size_t)b * N + n) * CKD + ty * 4] = h;
    }
}

// ---------------------------------------------------------------------------
// conv1x1 (fp32) whose input is x1+x2 (K-split recombine), for gamma conv.
// ---------------------------------------------------------------------------
__global__ __launch_bounds__(256) void conv1x1_sum2(
    const float* __restrict__ x1, const float* __restrict__ x2,
    const float* __restrict__ W, const float* __restrict__ bias,
    float* __restrict__ out, int Cin, int N)
{
    __shared__ float as[64][65];
    __shared__ float xs[64][64];
    const int tx = threadIdx.x, ty = threadIdx.y;
    const int t  = ty * 16 + tx;
    const int n0 = blockIdx.x * 64, o0 = blockIdx.y * 64, b = blockIdx.z;
    const int O  = gridDim.y * 64;
    const float* x1b = x1 + (size_t)b * Cin * N;
    const float* x2b = x2 + (size_t)b * Cin * N;

    float acc[4][4] = {};
    for (int c0 = 0; c0 < Cin; c0 += 64) {
        __syncthreads();
        #pragma unroll
        for (int it = 0; it < 16; ++it) {
            int flat = it * 256 + t;
            int row = flat >> 6, col = flat & 63;
            size_t gi = (size_t)(c0 + row) * N + n0 + col;
            as[row][col] = W[(size_t)(o0 + row) * Cin + c0 + col];
            xs[row][col] = x1b[gi] + x2b[gi];
        }
        __syncthreads();
        #pragma unroll
        for (int cc = 0; cc < 64; ++cc) {
            float4 xv = *(const float4*)&xs[cc][tx * 4];
            float a0 = as[ty * 4 + 0][cc];
            float a1 = as[ty * 4 + 1][cc];
            float a2 = as[ty * 4 + 2][cc];
            float a3 = as[ty * 4 + 3][cc];
            acc[0][0] += a0 * xv.x; acc[0][1] += a0 * xv.y; acc[0][2] += a0 * xv.z; acc[0][3] += a0 * xv.w;
            acc[1][0] += a1 * xv.x; acc[1][1] += a1 * xv.y; acc[1][2] += a1 * xv.z; acc[1][3] += a1 * xv.w;
            acc[2][0] += a2 * xv.x; acc[2][1] += a2 * xv.y; acc[2][2] += a2 * xv.z; acc[2][3] += a2 * xv.w;
            acc[3][0] += a3 * xv.x; acc[3][1] += a3 * xv.y; acc[3][2] += a3 * xv.z; acc[3][3] += a3 * xv.w;
        }
    }
    #pragma unroll
    for (int a = 0; a < 4; ++a) {
        int o = o0 + ty * 4 + a;
        float bv = bias[o];
        float4 r;
        r.x = acc[a][0] + bv; r.y = acc[a][1] + bv;
        r.z = acc[a][2] + bv; r.w = acc[a][3] + bv;
        *(float4*)&out[((size_t)b * O + o) * N + n0 + tx * 4] = r;
    }
}

// ---------------------------------------------------------------------------
// Energy via MFMA: e[i,j] = exp(qT_i . kT_j), fp32 accumulate/exp.
// Writes Et[b,j,i] fp16 (coalesced via LDS transpose) and row sums S[b,i]
// (reduced from the fp16-rounded LDS tile; quantization error ~5e-4 rel).
// A = qT (m=i), B = kT (n=j); mfma_f32_16x16x32_f16, K=64 = 2 steps.
// grid (N/64 j, N/64 i, B), block 256 (4 waves; wave w handles j-sub 16w x i 64)
// ---------------------------------------------------------------------------
__global__ __launch_bounds__(256) void energy_mfma(
    const f16* __restrict__ qT, const f16* __restrict__ kT,
    float* __restrict__ S, f16* __restrict__ Et)
{
    __shared__ f16   es[64][72];     // [j_local][i_local], padded (144B rows, 16B-aligned)
    __shared__ float red2[4][64];
    const int t    = threadIdx.x;
    const int w    = t >> 6, lane = t & 63;
    const int quad = lane >> 4, l16 = lane & 15;
    const int j0 = blockIdx.x * 64, i0 = blockIdx.y * 64, b = blockIdx.z;
    const f16* qb = qT + (size_t)b * NPIX * CKD;
    const f16* kb = kT + (size_t)b * NPIX * CKD;

    f32x4 acc[4];
    #pragma unroll
    for (int mt = 0; mt < 4; ++mt) acc[mt] = (f32x4){0.f, 0.f, 0.f, 0.f};

    #pragma unroll
    for (int ks = 0; ks < 2; ++ks) {
        f16x8 bf = *(const f16x8*)&kb[((size_t)(j0 + 16 * w + l16)) * CKD + ks * 32 + quad * 8];
        #pragma unroll
        for (int mt = 0; mt < 4; ++mt) {
            f16x8 af = *(const f16x8*)&qb[((size_t)(i0 + 16 * mt + l16)) * CKD + ks * 32 + quad * 8];
            acc[mt] = __builtin_amdgcn_mfma_f32_16x16x32_f16(af, bf, acc[mt], 0, 0, 0);
        }
    }

    // exp + write to LDS tile: lane owns (j = 16w+l16, i = 16mt+quad*4+r)
    #pragma unroll
    for (int mt = 0; mt < 4; ++mt) {
        f16x4 h = { (f16)__expf(acc[mt][0]), (f16)__expf(acc[mt][1]),
                    (f16)__expf(acc[mt][2]), (f16)__expf(acc[mt][3]) };
        *(f16x4*)&es[16 * w + l16][16 * mt + quad * 4] = h;
    }
    __syncthreads();

    // coalesced global store: thread t -> row j = t>>2, 32B chunk (t&3)
    {
        int j = t >> 2, ch = (t & 3) * 16;
        f16x8 v0 = *(const f16x8*)&es[j][ch];
        f16x8 v1 = *(const f16x8*)&es[j][ch + 8];
        f16* gp = &Et[((size_t)b * NPIX + j0 + j) * NPIX + i0 + ch];
        *(f16x8*)gp       = v0;
        *(f16x8*)(gp + 8) = v1;
    }
    // column partial sums (over j) for S
    {
        int i = t & 63, jq = t >> 6;
        float s = 0.f;
        #pragma unroll
        for (int jj = 0; jj < 16; ++jj)
            s += (float)es[jq * 16 + jj][i];
        red2[jq][i] = s;
    }
    __syncthreads();
    if (t < 64) {
        float s = red2[0][t] + red2[1][t] + red2[2][t] + red2[3][t];
        atomicAdd(&S[(size_t)b * NPIX + i0 + t], s);
    }
}

__global__ __launch_bounds__(256) void recip_kernel(
    const float* __restrict__ S, float* __restrict__ invS, int n)
{
    int i = blockIdx.x * 256 + threadIdx.x;
    if (i < n) invS[i] = 1.0f / S[i];
}

// ---------------------------------------------------------------------------
// u[b,c,i] = v[b,c,i] * invS[b,i], fp16
// ---------------------------------------------------------------------------
__global__ __launch_bounds__(256) void make_u(
    const float* __restrict__ v, const float* __restrict__ invS,
    f16* __restrict__ u)
{
    size_t idx = ((size_t)blockIdx.x * 256 + threadIdx.x) * 4;
    int i  = (int)(idx % NPIX);
    int b  = (int)(idx / ((size_t)CIN * NPIX));
    float4 vv = *(const float4*)(v + idx);
    float4 s  = *(const float4*)(invS + (size_t)b * NPIX + i);
    f16x4 h = { (f16)(vv.x * s.x), (f16)(vv.y * s.y),
                (f16)(vv.z * s.z), (f16)(vv.w * s.w) };
    *(f16x4*)(u + idx) = h;
}

// ---------------------------------------------------------------------------
// MFMA bmm, m97-style LDS-staged: out[b,c,j] = sum_i u[b,c,i]*Et[b,j,i]
// Tile 128(c) x 128(j), BK=32, K-split 2 (halves -> o1a/o1b).
// Block 256 thr = 4 waves in 2x2; wave computes 64x64 (4x4 of 16x16 tiles).
// LDS rows padded to 40 f16 (80B: 16B-aligned, conflict-spread).
// grid (N/128, C/128, B*2)
// ---------------------------------------------------------------------------
__global__ __launch_bounds__(256) void bmm_mfma(
    const f16* __restrict__ u, const f16* __restrict__ Et,
    float* __restrict__ o1a, float* __restrict__ o1b)
{
    __shared__ __align__(16) f16 As[128 * 40];
    __shared__ __align__(16) f16 Bs[128 * 40];
    const int t    = threadIdx.x;
    const int w    = t >> 6, lane = t & 63;
    const int quad = lane >> 4, l16 = lane & 15;
    const int wm = w & 1, wn = w >> 1;
    const int j0 = blockIdx.x * 128;
    const int c0 = blockIdx.y * 128;
    const int b  = blockIdx.z >> 1, ks = blockIdx.z & 1;
    const int kb = ks * KHALF;
    const f16* ub = u  + (size_t)b * CIN * NPIX;
    const f16* eb = Et + (size_t)b * NPIX * NPIX;
    float* outp = ks ? o1b : o1a;

    // staging: each thread carries one 16B chunk per 64-row half
    const int sub = lane >> 2, le = lane & 3;
    const f16* srcA = ub + (size_t)(c0 + 16 * w + sub) * NPIX + kb + le * 8;
    const f16* srcB = eb + (size_t)(j0 + 16 * w + sub) * NPIX + kb + le * 8;
    const int ldsw = (16 * w + sub) * 40 + le * 8;   // rows 16w..16w+15
    const size_t half = (size_t)64 * NPIX;           // +64 rows in global

    f32x4 acc[4][4];
    #pragma unroll
    for (int mt = 0; mt < 4; ++mt)
        #pragma unroll
        for (int nt = 0; nt < 4; ++nt)
            acc[mt][nt] = (f32x4){0.f, 0.f, 0.f, 0.f};

    for (int kk = 0; kk < KHALF; kk += 32) {
        f16x8 ta0 = *(const f16x8*)(srcA + kk);
        f16x8 ta1 = *(const f16x8*)(srcA + half + kk);
        f16x8 tb0 = *(const f16x8*)(srcB + kk);
        f16x8 tb1 = *(const f16x8*)(srcB + half + kk);
        __syncthreads();   // previous iteration's frag reads complete
        *(f16x8*)&As[ldsw]           = ta0;
        *(f16x8*)&As[64 * 40 + ldsw] = ta1;
        *(f16x8*)&Bs[ldsw]           = tb0;
        *(f16x8*)&Bs[64 * 40 + ldsw] = tb1;
        __syncthreads();
        f16x8 af[4], bf[4];
        #pragma unroll
        for (int mt = 0; mt < 4; ++mt)
            af[mt] = *(const f16x8*)&As[(64 * wm + 16 * mt + l16) * 40 + quad * 8];
        #pragma unroll
        for (int nt = 0; nt < 4; ++nt)
            bf[nt] = *(const f16x8*)&Bs[(64 * wn + 16 * nt + l16) * 40 + quad * 8];
        #pragma unroll
        for (int mt = 0; mt < 4; ++mt)
            #pragma unroll
            for (int nt = 0; nt < 4; ++nt)
                acc[mt][nt] = __builtin_amdgcn_mfma_f32_16x16x32_f16(
                    af[mt], bf[nt], acc[mt][nt], 0, 0, 0);
    }

    #pragma unroll
    for (int mt = 0; mt < 4; ++mt) {
        #pragma unroll
        for (int r = 0; r < 4; ++r) {
            int c = c0 + 64 * wm + 16 * mt + quad * 4 + r;
            float* op = &outp[((size_t)b * CIN + c) * NPIX + j0 + 64 * wn];
            #pragma unroll
            for (int nt = 0; nt < 4; ++nt)
                op[16 * nt + l16] = acc[mt][nt][r];
        }
    }
}

// ---------------------------------------------------------------------------
extern "C" void kernel_launch(void* const* d_in, const int* in_sizes, int n_in,
                              void* d_out, int out_size, void* d_ws, size_t ws_size,
                              hipStream_t stream) {
    const float* x  = (const float*)d_in[0];
    const float* qw = (const float*)d_in[1];
    const float* qbv= (const float*)d_in[2];
    const float* kw = (const float*)d_in[3];
    const float* kbv= (const float*)d_in[4];
    const float* vw = (const float*)d_in[5];
    const float* vbv= (const float*)d_in[6];
    const float* gw = (const float*)d_in[7];
    const float* gbv= (const float*)d_in[8];
    float* out = (float*)d_out;

    const size_t BCN  = (size_t)BATCH * CIN * NPIX;   // 4,718,592
    const size_t BN   = (size_t)BATCH * NPIX;         // 18,432
    const size_t BNN  = (size_t)BATCH * NPIX * NPIX;  // 42,467,328
    const size_t BNCK = (size_t)BATCH * NPIX * CKD;   // 1,179,648

    // ws layout (~137 MB): v aliases nothing until make_u consumes it, then
    // bmm writes o1a into the SAME region (v dead after make_u; stream-ordered).
    f16*   Et  = (f16*)d_ws;          // 84.93 MB
    f16*   u   = Et + BNN;            //  9.44 MB
    f16*   qT  = u + BCN;             //  2.36 MB
    f16*   kT  = qT + BNCK;           //  2.36 MB
    float* S   = (float*)(kT + BNCK); //  0.07 MB
    float* iS  = S + BN;              //  0.07 MB
    float* o1b = iS + BN;             // 18.87 MB
    float* v   = o1b + BCN;           // 18.87 MB (reused as o1a)
    float* o1a = v;

    hipMemsetAsync(S, 0, BN * sizeof(float), stream);

    dim3 blk(16, 16);
    conv1x1_qk_f16t<<<dim3(NPIX / 64, 1, BATCH), blk, 0, stream>>>(x, qw, qbv, qT, CIN, NPIX);
    conv1x1_qk_f16t<<<dim3(NPIX / 64, 1, BATCH), blk, 0, stream>>>(x, kw, kbv, kT, CIN, NPIX);
    conv1x1_gemm<<<dim3(NPIX / 64, CIN / 64, BATCH), blk, 0, stream>>>(x, vw, vbv, v, CIN, NPIX);
    energy_mfma<<<dim3(NPIX / 64, NPIX / 64, BATCH), 256, 0, stream>>>(qT, kT, S, Et);
    recip_kernel<<<(int)((BN + 255) / 256), 256, 0, stream>>>(S, iS, (int)BN);
    make_u<<<(int)(BCN / 4 / 256), 256, 0, stream>>>(v, iS, u);
    bmm_mfma<<<dim3(NPIX / 128, CIN / 128, BATCH * 2), 256, 0, stream>>>(u, Et, o1a, o1b);
    conv1x1_sum2<<<dim3(NPIX / 64, CIN / 64, BATCH), blk, 0, stream>>>(o1a, o1b, gw, gbv, out, CIN, NPIX);
}

// Round 4
// 245.812 us; speedup vs baseline: 5.2704x; 1.5114x over previous
//
#include <hip/hip_runtime.h>

// B=8, C=256, H=W=48 -> N=2304, k=4 -> CK=64
#define BATCH 8
#define CIN   256
#define NPIX  2304
#define CKD   64
#define KHALF (NPIX / 2)   // 1152
#define QKLD  128          // qkT row stride (q cols 0-63, k cols 64-127)

typedef _Float16 f16;
typedef __attribute__((ext_vector_type(4))) _Float16 f16x4;
typedef __attribute__((ext_vector_type(8))) _Float16 f16x8;
typedef __attribute__((ext_vector_type(4))) float    f32x4;

// ---------------------------------------------------------------------------
// Cast all conv weights fp32 -> f16. Wqk = [qw (64x256); kw (64x256)].
// 163840 elements total, 4 per thread.
// ---------------------------------------------------------------------------
__global__ __launch_bounds__(256) void cast_w(
    const float* __restrict__ qw, const float* __restrict__ kw,
    const float* __restrict__ vw, const float* __restrict__ gw,
    f16* __restrict__ Wqk, f16* __restrict__ Wv, f16* __restrict__ Wg)
{
    int idx = (blockIdx.x * 256 + threadIdx.x) * 4;
    const float* src;
    f16* dst;
    if (idx < 16384)      { src = qw + idx;           dst = Wqk + idx; }
    else if (idx < 32768) { src = kw + (idx - 16384); dst = Wqk + idx; }
    else if (idx < 98304) { src = vw + (idx - 32768); dst = Wv + (idx - 32768); }
    else                  { src = gw + (idx - 98304); dst = Wg + (idx - 98304); }
    float4 v = *(const float4*)src;
    f16x4 h = { (f16)v.x, (f16)v.y, (f16)v.z, (f16)v.w };
    *(f16x4*)dst = h;
}

// ---------------------------------------------------------------------------
// x[b][c][n] fp32 -> xT[b][n][c] f16 (LDS transpose). Tile 64c x 64n.
// grid (N/64, C/64, B), block 256.
// ---------------------------------------------------------------------------
__global__ __launch_bounds__(256) void cast_xT(
    const float* __restrict__ x, f16* __restrict__ xT)
{
    __shared__ float s[64][65];
    const int t = threadIdx.x;
    const int n0 = blockIdx.x * 64, c0 = blockIdx.y * 64, b = blockIdx.z;
    const float* xb = x + ((size_t)b * CIN + c0) * NPIX + n0;

    const int cl = t >> 4, ng = (t & 15) * 4;
    #pragma unroll
    for (int p = 0; p < 4; ++p) {
        float4 v = *(const float4*)(xb + (size_t)(cl + 16 * p) * NPIX + ng);
        s[cl + 16 * p][ng + 0] = v.x;
        s[cl + 16 * p][ng + 1] = v.y;
        s[cl + 16 * p][ng + 2] = v.z;
        s[cl + 16 * p][ng + 3] = v.w;
    }
    __syncthreads();
    const int nl = t >> 2, cs = (t & 3) * 16;
    f16 h[16];
    #pragma unroll
    for (int j = 0; j < 16; ++j) h[j] = (f16)s[cs + j][nl];
    f16* gp = &xT[((size_t)b * NPIX + n0 + nl) * CIN + c0 + cs];
    *(f16x8*)gp       = *(f16x8*)&h[0];
    *(f16x8*)(gp + 8) = *(f16x8*)&h[8];
}

// ---------------------------------------------------------------------------
// q & k conv via MFMA: qkT[b][n][o], o<64 = q, o>=64 = k.
// A = Wqk[o][c] f16, B = xT[n][c]. Direct-global fragments (W is L1/L2-hot).
// grid (N/32, B), block 256: wave wm=w&1 -> o-half, wn=w>>1 -> n-sub 16.
// ---------------------------------------------------------------------------
__global__ __launch_bounds__(256) void qk_conv_mfma(
    const f16* __restrict__ xT, const f16* __restrict__ Wqk,
    const float* __restrict__ qbias, const float* __restrict__ kbias,
    f16* __restrict__ qkT)
{
    const int t = threadIdx.x, w = t >> 6, lane = t & 63;
    const int quad = lane >> 4, l16 = lane & 15;
    const int wm = w & 1, wn = w >> 1;
    const int n0 = blockIdx.x * 32, b = blockIdx.y;

    const f16* bp = xT + ((size_t)b * NPIX + n0 + 16 * wn + l16) * CIN;
    const f16* ap = Wqk + (size_t)(64 * wm + l16) * CIN;

    f32x4 acc[4];
    #pragma unroll
    for (int mt = 0; mt < 4; ++mt) acc[mt] = (f32x4){0.f, 0.f, 0.f, 0.f};

    #pragma unroll
    for (int kk = 0; kk < CIN; kk += 32) {
        f16x8 bf = *(const f16x8*)(bp + kk + quad * 8);
        #pragma unroll
        for (int mt = 0; mt < 4; ++mt) {
            f16x8 af = *(const f16x8*)(ap + (size_t)mt * 16 * CIN + kk + quad * 8);
            acc[mt] = __builtin_amdgcn_mfma_f32_16x16x32_f16(af, bf, acc[mt], 0, 0, 0);
        }
    }
    const int n = n0 + 16 * wn + l16;
    const float* bias = wm ? kbias - 64 : qbias;   // o-indexed
    #pragma unroll
    for (int mt = 0; mt < 4; ++mt) {
        int ob = 64 * wm + 16 * mt + quad * 4;
        f16x4 h;
        #pragma unroll
        for (int r = 0; r < 4; ++r)
            h[r] = (f16)(acc[mt][r] + bias[ob + r]);
        *(f16x4*)&qkT[((size_t)b * NPIX + n) * QKLD + ob] = h;
    }
}

// ---------------------------------------------------------------------------
// Energy via MFMA: e[i,j] = exp(q_i . k_j). Writes Et[b,j,i] f16 (coalesced)
// and row sums S[b,i] (atomicAdd, from the f16-rounded tile).
// grid (N/64 j, N/64 i, B), block 256.
// ---------------------------------------------------------------------------
__global__ __launch_bounds__(256) void energy_mfma(
    const f16* __restrict__ qkT, float* __restrict__ S, f16* __restrict__ Et)
{
    __shared__ f16   es[64][72];
    __shared__ float red2[4][64];
    const int t    = threadIdx.x;
    const int w    = t >> 6, lane = t & 63;
    const int quad = lane >> 4, l16 = lane & 15;
    const int j0 = blockIdx.x * 64, i0 = blockIdx.y * 64, b = blockIdx.z;
    const f16* base = qkT + (size_t)b * NPIX * QKLD;

    f32x4 acc[4];
    #pragma unroll
    for (int mt = 0; mt < 4; ++mt) acc[mt] = (f32x4){0.f, 0.f, 0.f, 0.f};

    #pragma unroll
    for (int ks = 0; ks < 2; ++ks) {
        f16x8 bf = *(const f16x8*)&base[(size_t)(j0 + 16 * w + l16) * QKLD + 64 + ks * 32 + quad * 8];
        #pragma unroll
        for (int mt = 0; mt < 4; ++mt) {
            f16x8 af = *(const f16x8*)&base[(size_t)(i0 + 16 * mt + l16) * QKLD + ks * 32 + quad * 8];
            acc[mt] = __builtin_amdgcn_mfma_f32_16x16x32_f16(af, bf, acc[mt], 0, 0, 0);
        }
    }

    #pragma unroll
    for (int mt = 0; mt < 4; ++mt) {
        f16x4 h = { (f16)__expf(acc[mt][0]), (f16)__expf(acc[mt][1]),
                    (f16)__expf(acc[mt][2]), (f16)__expf(acc[mt][3]) };
        *(f16x4*)&es[16 * w + l16][16 * mt + quad * 4] = h;
    }
    __syncthreads();

    {
        int j = t >> 2, ch = (t & 3) * 16;
        f16x8 v0 = *(const f16x8*)&es[j][ch];
        f16x8 v1 = *(const f16x8*)&es[j][ch + 8];
        f16* gp = &Et[((size_t)b * NPIX + j0 + j) * NPIX + i0 + ch];
        *(f16x8*)gp       = v0;
        *(f16x8*)(gp + 8) = v1;
    }
    {
        int i = t & 63, jq = t >> 6;
        float s = 0.f;
        #pragma unroll
        for (int jj = 0; jj < 16; ++jj)
            s += (float)es[jq * 16 + jj][i];
        red2[jq][i] = s;
    }
    __syncthreads();
    if (t < 64) {
        float s = red2[0][t] + red2[1][t] + red2[2][t] + red2[3][t];
        atomicAdd(&S[(size_t)b * NPIX + i0 + t], s);
    }
}

__global__ __launch_bounds__(256) void recip_kernel(
    const float* __restrict__ S, float* __restrict__ invS, int n)
{
    int i = blockIdx.x * 256 + threadIdx.x;
    if (i < n) invS[i] = 1.0f / S[i];
}

// ---------------------------------------------------------------------------
// v conv via MFMA, fused bias + invS scale: u[b,c,i] = (sum_ch Wv[c,ch]*x[ch,i]
// + vbias[c]) * invS[b,i], f16 out. Tile 128(c) x 64(i), BK=32, LDS-staged.
// grid (N/64, C/128, B), block 256 (4 waves 2x2; wave = 64x32).
// ---------------------------------------------------------------------------
__global__ __launch_bounds__(256) void v_conv_mfma(
    const f16* __restrict__ xT, const f16* __restrict__ Wv,
    const float* __restrict__ vbias, const float* __restrict__ invS,
    f16* __restrict__ u)
{
    __shared__ __align__(16) f16 As[128 * 40];
    __shared__ __align__(16) f16 Bs[64 * 40];
    const int t = threadIdx.x, w = t >> 6, lane = t & 63;
    const int quad = lane >> 4, l16 = lane & 15;
    const int wm = w & 1, wn = w >> 1;
    const int i0 = blockIdx.x * 64, c0 = blockIdx.y * 128, b = blockIdx.z;
    const int sub = t >> 2, le = t & 3;
    const f16* srcA = Wv + (size_t)(c0 + sub) * CIN + le * 8;
    const f16* srcB = xT + ((size_t)b * NPIX + i0 + sub) * CIN + le * 8;
    const int ldsw = sub * 40 + le * 8;

    f32x4 acc[4][2];
    #pragma unroll
    for (int mt = 0; mt < 4; ++mt)
        #pragma unroll
        for (int nt = 0; nt < 2; ++nt)
            acc[mt][nt] = (f32x4){0.f, 0.f, 0.f, 0.f};

    for (int kk = 0; kk < CIN; kk += 32) {
        f16x8 ta0 = *(const f16x8*)(srcA + kk);
        f16x8 ta1 = *(const f16x8*)(srcA + (size_t)64 * CIN + kk);
        f16x8 tb0 = *(const f16x8*)(srcB + kk);
        __syncthreads();
        *(f16x8*)&As[ldsw]           = ta0;
        *(f16x8*)&As[64 * 40 + ldsw] = ta1;
        *(f16x8*)&Bs[ldsw]           = tb0;
        __syncthreads();
        f16x8 af[4], bf[2];
        #pragma unroll
        for (int mt = 0; mt < 4; ++mt)
            af[mt] = *(const f16x8*)&As[(64 * wm + 16 * mt + l16) * 40 + quad * 8];
        #pragma unroll
        for (int nt = 0; nt < 2; ++nt)
            bf[nt] = *(const f16x8*)&Bs[(32 * wn + 16 * nt + l16) * 40 + quad * 8];
        #pragma unroll
        for (int mt = 0; mt < 4; ++mt)
            #pragma unroll
            for (int nt = 0; nt < 2; ++nt)
                acc[mt][nt] = __builtin_amdgcn_mfma_f32_16x16x32_f16(
                    af[mt], bf[nt], acc[mt][nt], 0, 0, 0);
    }

    #pragma unroll
    for (int nt = 0; nt < 2; ++nt) {
        int i = i0 + 32 * wn + 16 * nt + l16;
        float is = invS[(size_t)b * NPIX + i];
        #pragma unroll
        for (int mt = 0; mt < 4; ++mt)
            #pragma unroll
            for (int r = 0; r < 4; ++r) {
                int c = c0 + 64 * wm + 16 * mt + quad * 4 + r;
                u[((size_t)b * CIN + c) * NPIX + i] =
                    (f16)((acc[mt][nt][r] + vbias[c]) * is);
            }
    }
}

// ---------------------------------------------------------------------------
// MFMA bmm: o1T[b,j,c] = sum_i u[b,c,i]*Et[b,j,i], K-split 2 -> o1aT/o1bT f16.
// Tile 128(c) x 128(j), BK=32. grid (N/128, C/128, B*2), block 256.
// ---------------------------------------------------------------------------
__global__ __launch_bounds__(256) void bmm_mfma(
    const f16* __restrict__ u, const f16* __restrict__ Et,
    f16* __restrict__ o1aT, f16* __restrict__ o1bT)
{
    __shared__ __align__(16) f16 As[128 * 40];
    __shared__ __align__(16) f16 Bs[128 * 40];
    const int t    = threadIdx.x;
    const int w    = t >> 6, lane = t & 63;
    const int quad = lane >> 4, l16 = lane & 15;
    const int wm = w & 1, wn = w >> 1;
    const int j0 = blockIdx.x * 128;
    const int c0 = blockIdx.y * 128;
    const int b  = blockIdx.z >> 1, ks = blockIdx.z & 1;
    const int kb = ks * KHALF;
    const f16* ub = u  + (size_t)b * CIN * NPIX;
    const f16* eb = Et + (size_t)b * NPIX * NPIX;
    f16* outp = ks ? o1bT : o1aT;

    const int sub = lane >> 2, le = lane & 3;
    const f16* srcA = ub + (size_t)(c0 + 16 * w + sub) * NPIX + kb + le * 8;
    const f16* srcB = eb + (size_t)(j0 + 16 * w + sub) * NPIX + kb + le * 8;
    const int ldsw = (16 * w + sub) * 40 + le * 8;
    const size_t half = (size_t)64 * NPIX;

    f32x4 acc[4][4];
    #pragma unroll
    for (int mt = 0; mt < 4; ++mt)
        #pragma unroll
        for (int nt = 0; nt < 4; ++nt)
            acc[mt][nt] = (f32x4){0.f, 0.f, 0.f, 0.f};

    for (int kk = 0; kk < KHALF; kk += 32) {
        f16x8 ta0 = *(const f16x8*)(srcA + kk);
        f16x8 ta1 = *(const f16x8*)(srcA + half + kk);
        f16x8 tb0 = *(const f16x8*)(srcB + kk);
        f16x8 tb1 = *(const f16x8*)(srcB + half + kk);
        __syncthreads();
        *(f16x8*)&As[ldsw]           = ta0;
        *(f16x8*)&As[64 * 40 + ldsw] = ta1;
        *(f16x8*)&Bs[ldsw]           = tb0;
        *(f16x8*)&Bs[64 * 40 + ldsw] = tb1;
        __syncthreads();
        f16x8 af[4], bf[4];
        #pragma unroll
        for (int mt = 0; mt < 4; ++mt)
            af[mt] = *(const f16x8*)&As[(64 * wm + 16 * mt + l16) * 40 + quad * 8];
        #pragma unroll
        for (int nt = 0; nt < 4; ++nt)
            bf[nt] = *(const f16x8*)&Bs[(64 * wn + 16 * nt + l16) * 40 + quad * 8];
        #pragma unroll
        for (int mt = 0; mt < 4; ++mt)
            #pragma unroll
            for (int nt = 0; nt < 4; ++nt)
                acc[mt][nt] = __builtin_amdgcn_mfma_f32_16x16x32_f16(
                    af[mt], bf[nt], acc[mt][nt], 0, 0, 0);
    }

    #pragma unroll
    for (int mt = 0; mt < 4; ++mt) {
        int cb = c0 + 64 * wm + 16 * mt + quad * 4;
        #pragma unroll
        for (int nt = 0; nt < 4; ++nt) {
            int j = j0 + 64 * wn + 16 * nt + l16;
            f16x4 h = { (f16)acc[mt][nt][0], (f16)acc[mt][nt][1],
                        (f16)acc[mt][nt][2], (f16)acc[mt][nt][3] };
            *(f16x4*)&outp[((size_t)b * NPIX + j) * CIN + cb] = h;
        }
    }
}

// ---------------------------------------------------------------------------
// Gamma conv via MFMA: out[b,o,j] = sum_c Wg[o,c]*(o1a[c,j]+o1b[c,j]) + gb[o]
// B staged as o1aT+o1bT (f16 add). Tile 128(o) x 64(j), BK=32, fp32 out.
// grid (N/64, C/128, B), block 256.
// ---------------------------------------------------------------------------
__global__ __launch_bounds__(256) void gamma_conv_mfma(
    const f16* __restrict__ o1aT, const f16* __restrict__ o1bT,
    const f16* __restrict__ Wg, const float* __restrict__ gbias,
    float* __restrict__ out)
{
    __shared__ __align__(16) f16 As[128 * 40];
    __shared__ __align__(16) f16 Bs[64 * 40];
    const int t = threadIdx.x, w = t >> 6, lane = t & 63;
    const int quad = lane >> 4, l16 = lane & 15;
    const int wm = w & 1, wn = w >> 1;
    const int j0 = blockIdx.x * 64, o0 = blockIdx.y * 128, b = blockIdx.z;
    const int sub = t >> 2, le = t & 3;
    const f16* srcA  = Wg + (size_t)(o0 + sub) * CIN + le * 8;
    const f16* srcB1 = o1aT + ((size_t)b * NPIX + j0 + sub) * CIN + le * 8;
    const f16* srcB2 = o1bT + ((size_t)b * NPIX + j0 + sub) * CIN + le * 8;
    const int ldsw = sub * 40 + le * 8;

    f32x4 acc[4][2];
    #pragma unroll
    for (int mt = 0; mt < 4; ++mt)
        #pragma unroll
        for (int nt = 0; nt < 2; ++nt)
            acc[mt][nt] = (f32x4){0.f, 0.f, 0.f, 0.f};

    for (int kk = 0; kk < CIN; kk += 32) {
        f16x8 ta0 = *(const f16x8*)(srcA + kk);
        f16x8 ta1 = *(const f16x8*)(srcA + (size_t)64 * CIN + kk);
        f16x8 tb1 = *(const f16x8*)(srcB1 + kk);
        f16x8 tb2 = *(const f16x8*)(srcB2 + kk);
        f16x8 tb0 = tb1 + tb2;
        __syncthreads();
        *(f16x8*)&As[ldsw]           = ta0;
        *(f16x8*)&As[64 * 40 + ldsw] = ta1;
        *(f16x8*)&Bs[ldsw]           = tb0;
        __syncthreads();
        f16x8 af[4], bf[2];
        #pragma unroll
        for (int mt = 0; mt < 4; ++mt)
            af[mt] = *(const f16x8*)&As[(64 * wm + 16 * mt + l16) * 40 + quad * 8];
        #pragma unroll
        for (int nt = 0; nt < 2; ++nt)
            bf[nt] = *(const f16x8*)&Bs[(32 * wn + 16 * nt + l16) * 40 + quad * 8];
        #pragma unroll
        for (int mt = 0; mt < 4; ++mt)
            #pragma unroll
            for (int nt = 0; nt < 2; ++nt)
                acc[mt][nt] = __builtin_amdgcn_mfma_f32_16x16x32_f16(
                    af[mt], bf[nt], acc[mt][nt], 0, 0, 0);
    }

    #pragma unroll
    for (int mt = 0; mt < 4; ++mt)
        #pragma unroll
        for (int r = 0; r < 4; ++r) {
            int o = o0 + 64 * wm + 16 * mt + quad * 4 + r;
            float bv = gbias[o];
            #pragma unroll
            for (int nt = 0; nt < 2; ++nt) {
                int j = j0 + 32 * wn + 16 * nt + l16;
                out[((size_t)b * CIN + o) * NPIX + j] = acc[mt][nt][r] + bv;
            }
        }
}

// ---------------------------------------------------------------------------
extern "C" void kernel_launch(void* const* d_in, const int* in_sizes, int n_in,
                              void* d_out, int out_size, void* d_ws, size_t ws_size,
                              hipStream_t stream) {
    const float* x   = (const float*)d_in[0];
    const float* qw  = (const float*)d_in[1];
    const float* qbv = (const float*)d_in[2];
    const float* kw  = (const float*)d_in[3];
    const float* kbv = (const float*)d_in[4];
    const float* vw  = (const float*)d_in[5];
    const float* vbv = (const float*)d_in[6];
    const float* gw  = (const float*)d_in[7];
    const float* gbv = (const float*)d_in[8];
    float* out = (float*)d_out;

    const size_t BCN  = (size_t)BATCH * CIN * NPIX;   // 4,718,592
    const size_t BN   = (size_t)BATCH * NPIX;         // 18,432
    const size_t BNN  = (size_t)BATCH * NPIX * NPIX;  // 42,467,328
    const size_t BNQK = (size_t)BATCH * NPIX * QKLD;  // 2,359,296

    // ws layout (~128 MB, all f16 except S/iS)
    f16* Et   = (f16*)d_ws;
    f16* u    = Et + BNN;
    f16* xT   = u + BCN;
    f16* qkT  = xT + BCN;
    f16* o1aT = qkT + BNQK;
    f16* o1bT = o1aT + BCN;
    f16* Wqk  = o1bT + BCN;
    f16* Wv   = Wqk + 128 * 256;
    f16* Wg   = Wv + 256 * 256;
    float* S  = (float*)(Wg + 256 * 256);
    float* iS = S + BN;

    hipMemsetAsync(S, 0, BN * sizeof(float), stream);

    cast_w<<<160, 256, 0, stream>>>(qw, kw, vw, gw, Wqk, Wv, Wg);
    cast_xT<<<dim3(NPIX / 64, CIN / 64, BATCH), 256, 0, stream>>>(x, xT);
    qk_conv_mfma<<<dim3(NPIX / 32, BATCH), 256, 0, stream>>>(xT, Wqk, qbv, kbv, qkT);
    energy_mfma<<<dim3(NPIX / 64, NPIX / 64, BATCH), 256, 0, stream>>>(qkT, S, Et);
    recip_kernel<<<(int)((BN + 255) / 256), 256, 0, stream>>>(S, iS, (int)BN);
    v_conv_mfma<<<dim3(NPIX / 64, CIN / 128, BATCH), 256, 0, stream>>>(xT, Wv, vbv, iS, u);
    bmm_mfma<<<dim3(NPIX / 128, CIN / 128, BATCH * 2), 256, 0, stream>>>(u, Et, o1aT, o1bT);
    gamma_conv_mfma<<<dim3(NPIX / 64, CIN / 128, BATCH), 256, 0, stream>>>(o1aT, o1bT, Wg, gbv, out);
}